// Round 2
// baseline (38.294 us; speedup 1.0000x reference)
//
#include <hip/hip_runtime.h>
#include <hip/hip_bf16.h>

#define BB 8
#define NN 256
#define DD 64
#define HH 8
#define PP 4

#define TI 32
#define TJ 16

typedef __attribute__((ext_vector_type(8))) short bf16x8;
typedef __attribute__((ext_vector_type(4))) float f32x4;

static __device__ __forceinline__ unsigned short bfbits(float f) {
  union { float f; unsigned u; } v; v.f = f;
  unsigned u = v.u;
  u += 0x7FFFu + ((u >> 16) & 1u);   // round-to-nearest-even
  return (unsigned short)(u >> 16);
}

static __device__ __forceinline__ bf16x8 pack8(float4 a, float4 b) {
  bf16x8 v;
  v[0] = (short)bfbits(a.x); v[1] = (short)bfbits(a.y);
  v[2] = (short)bfbits(a.z); v[3] = (short)bfbits(a.w);
  v[4] = (short)bfbits(b.x); v[5] = (short)bfbits(b.y);
  v[6] = (short)bfbits(b.z); v[7] = (short)bfbits(b.w);
  return v;
}

// Z[b][h][ki][j][d] = sum_kj conv_w[h][d][ki][kj] * x[b][j+kj-1][d]   (bf16 out)
__global__ __launch_bounds__(256)
void z_kernel(const float* __restrict__ x, const float* __restrict__ conv_w,
              unsigned short* __restrict__ z) {
  int t = blockIdx.x * 256 + threadIdx.x;        // B*H*3*N*(D/4) = 786432 threads
  int d4  = (t & 15) * 4;
  int row = t >> 4;                              // ((b*H + h)*3 + ki)*N + j
  int j   = row & (NN - 1);
  int r2  = row >> 8;
  int ki  = r2 % 3;
  int r3  = r2 / 3;
  int h   = r3 & (HH - 1);
  int b   = r3 >> 3;

  float a0 = 0.f, a1 = 0.f, a2 = 0.f, a3 = 0.f;
#pragma unroll
  for (int kj = 0; kj < 3; ++kj) {
    int js = j + kj - 1;
    if (js < 0 || js >= NN) continue;
    float4 xv = *(const float4*)(x + ((size_t)(b * NN + js)) * DD + d4);
    float w0 = conv_w[((h * DD + d4 + 0) * 3 + ki) * 3 + kj];
    float w1 = conv_w[((h * DD + d4 + 1) * 3 + ki) * 3 + kj];
    float w2 = conv_w[((h * DD + d4 + 2) * 3 + ki) * 3 + kj];
    float w3 = conv_w[((h * DD + d4 + 3) * 3 + ki) * 3 + kj];
    a0 += w0 * xv.x; a1 += w1 * xv.y; a2 += w2 * xv.z; a3 += w3 * xv.w;
  }
  ushort4 o;
  o.x = bfbits(a0); o.y = bfbits(a1); o.z = bfbits(a2); o.w = bfbits(a3);
  *(ushort4*)(z + (size_t)row * DD + d4) = o;
}

// out[b,h,i,j] = (sum_ki sum_d x[b,i+ki-1,d]*Z[b,h,ki][j,d] + conv_b[h]) * (edge[b,i,j,:]·edge_w[h,:])
// Tile: TI=32 x TJ=16 per block; 4 waves split 2x2 over (row-half, head-half).
// Grid = B * 8 * 16 = 1024 blocks -> 4 blocks/CU, 4 waves/SIMD.
__global__ __launch_bounds__(256, 4)
void main_kernel(const float* __restrict__ x, const unsigned short* __restrict__ z,
                 const float* __restrict__ edge, const float* __restrict__ conv_b,
                 const float* __restrict__ edge_w, float* __restrict__ out) {
  const int bid = blockIdx.x;            // b*(8*16) + it*16 + jt
  const int jt = bid & 15;
  const int it = (bid >> 4) & 7;
  const int b  = bid >> 7;
  const int lane = threadIdx.x & 63;
  const int wave = threadIdx.x >> 6;
  const int lrow = lane & 15;            // frag row (A) / col (B,C)
  const int lk   = lane >> 4;            // k-chunk 0..3

  const int rw = wave >> 1;              // row half within tile
  const int h0 = (wave & 1) * 4;         // head half
  const int i0 = it * TI + rw * 16;
  const int j0 = jt * TJ;

  // A fragments: rows i0..i0+15 with +-1 halo, fp32->bf16 on the fly
  bf16x8 a[3][2];
#pragma unroll
  for (int ki = 0; ki < 3; ++ki) {
    int r = i0 + lrow + ki - 1;
    bool ok = (r >= 0) && (r < NN);
#pragma unroll
    for (int dh = 0; dh < 2; ++dh) {
      bf16x8 v = {0, 0, 0, 0, 0, 0, 0, 0};
      if (ok) {
        const float* px = x + ((size_t)(b * NN + r)) * DD + dh * 32 + lk * 8;
        float4 f0 = *(const float4*)(px);
        float4 f1 = *(const float4*)(px + 4);
        v = pack8(f0, f1);
      }
      a[ki][dh] = v;
    }
  }

  // edge prefetch (hide latency under the MFMA loop)
  float4 e4[4];
#pragma unroll
  for (int r = 0; r < 4; ++r) {
    int i = i0 + lk * 4 + r;
    e4[r] = *(const float4*)(edge + ((size_t)(b * NN + i) * NN + (j0 + lrow)) * PP);
  }

  // per-head constants (this wave's 4 heads)
  float4 ew[4];
  float  cb4[4];
#pragma unroll
  for (int hh = 0; hh < 4; ++hh) {
    ew[hh] = *(const float4*)(edge_w + (h0 + hh) * PP);
    cb4[hh] = conv_b[h0 + hh];
  }

  f32x4 acc[4];
#pragma unroll
  for (int hh = 0; hh < 4; ++hh) acc[hh] = (f32x4){0.f, 0.f, 0.f, 0.f};

#pragma unroll
  for (int hh = 0; hh < 4; ++hh) {
    int h = h0 + hh;
#pragma unroll
    for (int ki = 0; ki < 3; ++ki) {
#pragma unroll
      for (int dh = 0; dh < 2; ++dh) {
        const unsigned short* pz =
            z + (((size_t)((b * HH + h) * 3 + ki) * NN + (j0 + lrow)) * DD + dh * 32 + lk * 8);
        bf16x8 bz = *(const bf16x8*)pz;
        acc[hh] = __builtin_amdgcn_mfma_f32_16x16x32_bf16(a[ki][dh], bz, acc[hh], 0, 0, 0);
      }
    }
  }

  // epilogue: edge projection + scale + store
#pragma unroll
  for (int r = 0; r < 4; ++r) {
    int i = i0 + lk * 4 + r;
    int j = j0 + lrow;
#pragma unroll
    for (int hh = 0; hh < 4; ++hh) {
      float eh = e4[r].x * ew[hh].x + e4[r].y * ew[hh].y +
                 e4[r].z * ew[hh].z + e4[r].w * ew[hh].w;
      out[((size_t)(b * HH + h0 + hh) * NN + i) * NN + j] = (acc[hh][r] + cb4[hh]) * eh;
    }
  }
}

extern "C" void kernel_launch(void* const* d_in, const int* in_sizes, int n_in,
                              void* d_out, int out_size, void* d_ws, size_t ws_size,
                              hipStream_t stream) {
  const float* x      = (const float*)d_in[0];
  const float* edge   = (const float*)d_in[1];
  const float* conv_w = (const float*)d_in[2];
  const float* conv_b = (const float*)d_in[3];
  const float* edge_w = (const float*)d_in[4];
  float* out = (float*)d_out;
  unsigned short* z = (unsigned short*)d_ws;   // B*H*3*N*D bf16 = 6.3 MB

  z_kernel<<<(BB * HH * 3 * NN * (DD / 4)) / 256, 256, 0, stream>>>(x, conv_w, z);
  main_kernel<<<BB * (NN / TI) * (NN / TJ), 256, 0, stream>>>(x, z, edge, conv_b, edge_w, out);
}

// Round 3
// 18.054 us; speedup vs baseline: 2.1211x; 2.1211x over previous
//
#include <hip/hip_runtime.h>
#include <hip/hip_bf16.h>

#define BB 8
#define NN 256
#define DD 64
#define HH 8
#define PP 4

typedef __attribute__((ext_vector_type(8))) short bf16x8;
typedef __attribute__((ext_vector_type(4))) float f32x4;

static __device__ __forceinline__ unsigned short bfbits(float f) {
  union { float f; unsigned u; } v; v.f = f;
  unsigned u = v.u;
  u += 0x7FFFu + ((u >> 16) & 1u);   // round-to-nearest-even
  return (unsigned short)(u >> 16);
}

static __device__ __forceinline__ bf16x8 pack8(float4 a, float4 b) {
  bf16x8 v;
  v[0] = (short)bfbits(a.x); v[1] = (short)bfbits(a.y);
  v[2] = (short)bfbits(a.z); v[3] = (short)bfbits(a.w);
  v[4] = (short)bfbits(b.x); v[5] = (short)bfbits(b.y);
  v[6] = (short)bfbits(b.z); v[7] = (short)bfbits(b.w);
  return v;
}

// LDS fragment address: fidx in [0,48), lane in [0,64), 16B units.
// XOR swizzle breaks write-phase bank conflicts; read side stays a
// permutation within each 128B block (contiguous-1KB wave read = conflict-free).
static __device__ __forceinline__ int frag_addr(int fidx, int lane) {
  return ((fidx * 64 + lane) * 16) ^ ((((lane >> 3) ^ fidx) & 7) << 4);
}

// Fused: Z = conv-row-factor in LDS (bf16 MFMA-fragment layout), then
// out[b,h,i,j] = (sum_ki sum_d x[b,i+ki-1,d]*Z[h,ki,j,d] + conv_b[h]) * (edge[b,i,j,:]. edge_w[h,:])
// Tile: 64 rows x 16 cols x all 8 heads per block. Grid = 8b*4it*16jt = 512.
__global__ __launch_bounds__(256, 3)
void fused_kernel(const float* __restrict__ x, const float* __restrict__ edge,
                  const float* __restrict__ conv_w, const float* __restrict__ conv_b,
                  const float* __restrict__ edge_w, float* __restrict__ out) {
  __shared__ bf16x8 frag_s[48 * 64];     // 49152 B
  char* fragb = (char*)frag_s;

  const int bid = blockIdx.x;
  const int jt = bid & 15;
  const int it = (bid >> 4) & 3;
  const int b  = bid >> 6;
  const int j0 = jt * 16;
  const int tid  = threadIdx.x;
  const int lane = tid & 63;
  const int wave = tid >> 6;
  const int lrow = lane & 15;            // A-frag row / B col / C col
  const int lkk  = lane >> 4;            // k-octet / C row-quad
  const int i0   = it * 64 + wave * 16;  // this wave's 16 output rows

  // ---- A fragments: rows i0..i0+15 with +-1 halo (SAME padding), fp32->bf16 ----
  bf16x8 a[3][2];
#pragma unroll
  for (int ki = 0; ki < 3; ++ki) {
    int r = i0 + lrow + ki - 1;
    bool ok = (r >= 0) && (r < NN);
#pragma unroll
    for (int dh = 0; dh < 2; ++dh) {
      bf16x8 v = {0, 0, 0, 0, 0, 0, 0, 0};
      if (ok) {
        const float* px = x + ((size_t)(b * NN + r)) * DD + dh * 32 + lkk * 8;
        float4 f0 = *(const float4*)(px);
        float4 f1 = *(const float4*)(px + 4);
        v = pack8(f0, f1);
      }
      a[ki][dh] = v;
    }
  }

  // ---- Z compute into LDS, fragment layout ----
  // thread -> (head zh, d-octet zo, j-quartet zjq); 12 fragment units each
  {
    const int zh  = tid >> 5;
    const int zo  = (tid >> 2) & 7;
    const int zjq = tid & 3;
    const int zd0 = zo * 8;

    float xv[6][8];
#pragma unroll
    for (int m = 0; m < 6; ++m) {
      int jg = j0 + zjq * 4 - 1 + m;
      if (jg >= 0 && jg < NN) {
        const float* px = x + ((size_t)(b * NN + jg)) * DD + zd0;
        float4 f0 = *(const float4*)(px);
        float4 f1 = *(const float4*)(px + 4);
        xv[m][0] = f0.x; xv[m][1] = f0.y; xv[m][2] = f0.z; xv[m][3] = f0.w;
        xv[m][4] = f1.x; xv[m][5] = f1.y; xv[m][6] = f1.z; xv[m][7] = f1.w;
      } else {
#pragma unroll
        for (int e = 0; e < 8; ++e) xv[m][e] = 0.f;
      }
    }

#pragma unroll
    for (int ki = 0; ki < 3; ++ki) {
      float wv[8][3];
#pragma unroll
      for (int e = 0; e < 8; ++e) {
        const float* pw = conv_w + (size_t)(zh * DD + zd0 + e) * 9 + ki * 3;
        wv[e][0] = pw[0]; wv[e][1] = pw[1]; wv[e][2] = pw[2];
      }
      int fidx = (zh * 3 + ki) * 2 + (zo >> 2);
#pragma unroll
      for (int jj = 0; jj < 4; ++jj) {
        bf16x8 v;
#pragma unroll
        for (int e = 0; e < 8; ++e) {
          float s = wv[e][0] * xv[jj][e] + wv[e][1] * xv[jj + 1][e] +
                    wv[e][2] * xv[jj + 2][e];
          v[e] = (short)bfbits(s);
        }
        int lw = (zo & 3) * 16 + zjq * 4 + jj;
        *(bf16x8*)(fragb + frag_addr(fidx, lw)) = v;
      }
    }
  }
  __syncthreads();

  // ---- edge prefetch (this wave's 16 rows x 16 cols, read exactly once/block) ----
  float4 e4[4];
#pragma unroll
  for (int r = 0; r < 4; ++r) {
    int i = i0 + lkk * 4 + r;
    e4[r] = *(const float4*)(edge + ((size_t)(b * NN + i) * NN + (j0 + lrow)) * PP);
  }

  // ---- MFMA: 8 heads x 3 ki x 2 dh = 48 per wave ----
  f32x4 acc[HH];
#pragma unroll
  for (int h = 0; h < HH; ++h) acc[h] = (f32x4){0.f, 0.f, 0.f, 0.f};

#pragma unroll
  for (int h = 0; h < HH; ++h) {
#pragma unroll
    for (int ki = 0; ki < 3; ++ki) {
#pragma unroll
      for (int dh = 0; dh < 2; ++dh) {
        int fidx = (h * 3 + ki) * 2 + dh;
        bf16x8 bz = *(const bf16x8*)(fragb + frag_addr(fidx, lane));
        acc[h] = __builtin_amdgcn_mfma_f32_16x16x32_bf16(a[ki][dh], bz, acc[h], 0, 0, 0);
      }
    }
  }

  // ---- epilogue: edge projection + scale + store ----
  float4 ew[HH];
  float  cb[HH];
#pragma unroll
  for (int h = 0; h < HH; ++h) {
    ew[h] = *(const float4*)(edge_w + h * PP);
    cb[h] = conv_b[h];
  }

#pragma unroll
  for (int r = 0; r < 4; ++r) {
    int i = i0 + lkk * 4 + r;
    int j = j0 + lrow;
#pragma unroll
    for (int h = 0; h < HH; ++h) {
      float eh = e4[r].x * ew[h].x + e4[r].y * ew[h].y +
                 e4[r].z * ew[h].z + e4[r].w * ew[h].w;
      out[((size_t)(b * HH + h) * NN + i) * NN + j] = (acc[h][r] + cb[h]) * eh;
    }
  }
}

extern "C" void kernel_launch(void* const* d_in, const int* in_sizes, int n_in,
                              void* d_out, int out_size, void* d_ws, size_t ws_size,
                              hipStream_t stream) {
  const float* x      = (const float*)d_in[0];
  const float* edge   = (const float*)d_in[1];
  const float* conv_w = (const float*)d_in[2];
  const float* conv_b = (const float*)d_in[3];
  const float* edge_w = (const float*)d_in[4];
  float* out = (float*)d_out;

  fused_kernel<<<BB * 4 * 16, 256, 0, stream>>>(x, edge, conv_w, conv_b, edge_w, out);
}